// Round 1
// baseline (8375.862 us; speedup 1.0000x reference)
//
#include <hip/hip_runtime.h>
#include <math.h>

#define T_TOKENS 4096
#define D_DIM    1024
#define E_EXP    8
#define H_DIM    4096

#define BT 128
#define BH 128

__device__ __forceinline__ unsigned short f2bf(float f) {
    unsigned int u = __float_as_uint(f);
    u += 0x7fffu + ((u >> 16) & 1u);
    return (unsigned short)(u >> 16);
}
__device__ __forceinline__ float bf2f(unsigned short s) {
    return __uint_as_float(((unsigned int)s) << 16);
}

// ---------------- Router: scores, top-2, softmax weights, expert bucketing ----
// One 64-lane wave per token; block = 256 threads = 4 tokens.
__global__ __launch_bounds__(256)
void moe_router_kernel(const float* __restrict__ x,
                       const float* __restrict__ Wr,
                       const float* __restrict__ br,
                       const float* __restrict__ b2,
                       float* __restrict__ out,
                       int* __restrict__ counts,
                       int* __restrict__ tok_id,
                       float* __restrict__ tok_w)
{
    const int token = blockIdx.x * 4 + (threadIdx.x >> 6);
    const int lane  = threadIdx.x & 63;

    float s[E_EXP];
#pragma unroll
    for (int e = 0; e < E_EXP; e++) s[e] = 0.0f;

    const float* xrow = x + (size_t)token * D_DIM;
#pragma unroll
    for (int i = 0; i < D_DIM / 64; i++) {
        int d = lane + 64 * i;
        float xv = xrow[d];
        const float4* wr4 = (const float4*)(Wr + (size_t)d * E_EXP);
        float4 w0 = wr4[0], w1 = wr4[1];
        s[0] = fmaf(xv, w0.x, s[0]); s[1] = fmaf(xv, w0.y, s[1]);
        s[2] = fmaf(xv, w0.z, s[2]); s[3] = fmaf(xv, w0.w, s[3]);
        s[4] = fmaf(xv, w1.x, s[4]); s[5] = fmaf(xv, w1.y, s[5]);
        s[6] = fmaf(xv, w1.z, s[6]); s[7] = fmaf(xv, w1.w, s[7]);
    }
    // 64-lane butterfly reduction; all lanes end with full sums.
#pragma unroll
    for (int off = 32; off >= 1; off >>= 1) {
#pragma unroll
        for (int e = 0; e < E_EXP; e++) s[e] += __shfl_xor(s[e], off, 64);
    }
#pragma unroll
    for (int e = 0; e < E_EXP; e++) s[e] += br[e];

    // top-2, ties -> lower index (matches jax.lax.top_k)
    int e0 = 0; float v0 = s[0];
#pragma unroll
    for (int e = 1; e < E_EXP; e++) if (s[e] > v0) { v0 = s[e]; e0 = e; }
    int e1 = (e0 == 0) ? 1 : 0; float v1 = s[e1];
#pragma unroll
    for (int e = 0; e < E_EXP; e++)
        if (e != e0 && s[e] > v1) { v1 = s[e]; e1 = e; }

    // softmax over the two selected scores (v0 >= v1)
    float p1 = __expf(v1 - v0);
    float inv = 1.0f / (1.0f + p1);
    float w0 = inv, w1 = p1 * inv;

    if (lane == 0) {
        int slot0 = atomicAdd(&counts[e0], 1);
        tok_id[e0 * T_TOKENS + slot0] = token;
        tok_w [e0 * T_TOKENS + slot0] = w0;
        int slot1 = atomicAdd(&counts[e1], 1);
        tok_id[e1 * T_TOKENS + slot1] = token;
        tok_w [e1 * T_TOKENS + slot1] = w1;
    }

    // out = w0*b2[e0] + w1*b2[e1]  (expert GEMM adds on top via atomics)
    float* orow = out + (size_t)token * D_DIM;
    const float* b20 = b2 + (size_t)e0 * D_DIM;
    const float* b21 = b2 + (size_t)e1 * D_DIM;
#pragma unroll
    for (int i = 0; i < D_DIM / 64; i++) {
        int d = lane + 64 * i;
        orow[d] = fmaf(w0, b20[d], w1 * b21[d]);
    }
}

// ---------------- Fused grouped FFN: h = relu(Xg@W1+b1)*w ; out += h@W2 ------
// grid: (H/BH, maxTiles=32, E). 256 threads, 8x8 micro-tile per thread.
__global__ __launch_bounds__(256, 3)
void moe_ffn_kernel(const float* __restrict__ x,
                    const float* __restrict__ W1,
                    const float* __restrict__ b1,
                    const float* __restrict__ W2,
                    float* __restrict__ out,
                    const int* __restrict__ counts,
                    const int* __restrict__ tok_id,
                    const float* __restrict__ tok_w)
{
    const int e   = blockIdx.z;
    const int n_e = counts[e];
    const int m0  = blockIdx.y * BT;
    if (m0 >= n_e) return;
    const int h0  = blockIdx.x * BH;
    const int tid = threadIdx.x;
    const int ty  = tid >> 4;   // 0..15
    const int tx  = tid & 15;   // 0..15

    // 50688 B pool: [0,4224) stage (32x132), [4224,12672) xs (128x33) / hs bf16 (128x132)
    __shared__ float pool[12672];
    __shared__ int   ids_s[BT];
    __shared__ float wts_s[BT];
    float* stage = pool;
    float* xs    = pool + 4224;
    unsigned short* hs = (unsigned short*)(pool + 4224);

    if (tid < BT) {
        int slot = m0 + tid;
        if (slot < n_e) {
            ids_s[tid] = tok_id[e * T_TOKENS + slot];
            wts_s[tid] = tok_w[e * T_TOKENS + slot];
        } else {
            ids_s[tid] = 0;      // safe gather target; contribution discarded
            wts_s[tid] = 0.0f;
        }
    }

    const float* W1e = W1 + (size_t)e * D_DIM * H_DIM;
    const float* W2e = W2 + (size_t)e * H_DIM * D_DIM;

    float acc[8][8];
#pragma unroll
    for (int i = 0; i < 8; i++)
#pragma unroll
        for (int j = 0; j < 8; j++) acc[i][j] = 0.0f;

    __syncthreads();

    // ---- Phase 1: h_tile[128x128] = Xg[128x1024] @ W1[:, h0:h0+128] ----
    for (int kk = 0; kk < D_DIM; kk += 32) {
#pragma unroll
        for (int it = 0; it < 4; it++) {          // X gather: 128 rows x 32 k
            int idx = tid + 256 * it;
            int r  = idx >> 3;
            int c4 = (idx & 7) << 2;
            const float* src = x + (size_t)ids_s[r] * D_DIM + kk + c4;
            float4 v = *(const float4*)src;
            float* dst = &xs[r * 33 + c4];
            dst[0] = v.x; dst[1] = v.y; dst[2] = v.z; dst[3] = v.w;
        }
#pragma unroll
        for (int it = 0; it < 4; it++) {          // W1 chunk: 32 k x 128 h
            int idx = tid + 256 * it;
            int k  = idx >> 5;
            int c4 = (idx & 31) << 2;
            const float* src = W1e + (size_t)(kk + k) * H_DIM + h0 + c4;
            float4 v = *(const float4*)src;
            float* dst = &stage[k * 132 + c4];
            dst[0] = v.x; dst[1] = v.y; dst[2] = v.z; dst[3] = v.w;
        }
        __syncthreads();
#pragma unroll 4
        for (int k = 0; k < 32; k++) {
            float a[8];
#pragma unroll
            for (int i = 0; i < 8; i++) a[i] = xs[(ty * 8 + i) * 33 + k];
            float4 blo = *(const float4*)&stage[k * 132 + tx * 8];
            float4 bhi = *(const float4*)&stage[k * 132 + tx * 8 + 4];
            float b[8] = {blo.x, blo.y, blo.z, blo.w, bhi.x, bhi.y, bhi.z, bhi.w};
#pragma unroll
            for (int i = 0; i < 8; i++)
#pragma unroll
                for (int j = 0; j < 8; j++)
                    acc[i][j] = fmaf(a[i], b[j], acc[i][j]);
        }
        __syncthreads();   // xs/stage free for next iteration (and hs aliasing)
    }

    // epilogue: bias + relu + token-weight scale, h -> LDS bf16
    {
        const float* b1e = b1 + (size_t)e * H_DIM + h0;
        float bv[8];
#pragma unroll
        for (int j = 0; j < 8; j++) bv[j] = b1e[tx * 8 + j];
#pragma unroll
        for (int i = 0; i < 8; i++) {
            float w = wts_s[ty * 8 + i];
#pragma unroll
            for (int j = 0; j < 8; j++) {
                float h = acc[i][j] + bv[j];
                h = fmaxf(h, 0.0f) * w;
                hs[(ty * 8 + i) * 132 + tx * 8 + j] = f2bf(h);
            }
        }
    }
    __syncthreads();

    // ---- Phase 2: out[128 x 1024] += h_tile @ W2[h0:h0+128, :] ----
    for (int dd = 0; dd < D_DIM; dd += 128) {
        float c2[8][8];
#pragma unroll
        for (int i = 0; i < 8; i++)
#pragma unroll
            for (int j = 0; j < 8; j++) c2[i][j] = 0.0f;

        for (int kc = 0; kc < BH; kc += 32) {
#pragma unroll
            for (int it = 0; it < 4; it++) {      // W2 chunk: 32 h x 128 d
                int idx = tid + 256 * it;
                int k  = idx >> 5;
                int c4 = (idx & 31) << 2;
                const float* src = W2e + (size_t)(h0 + kc + k) * D_DIM + dd + c4;
                float4 v = *(const float4*)src;
                float* dst = &stage[k * 132 + c4];
                dst[0] = v.x; dst[1] = v.y; dst[2] = v.z; dst[3] = v.w;
            }
            __syncthreads();
#pragma unroll 4
            for (int k = 0; k < 32; k++) {
                float a[8];
#pragma unroll
                for (int i = 0; i < 8; i++)
                    a[i] = bf2f(hs[(ty * 8 + i) * 132 + kc + k]);
                float4 blo = *(const float4*)&stage[k * 132 + tx * 8];
                float4 bhi = *(const float4*)&stage[k * 132 + tx * 8 + 4];
                float b[8] = {blo.x, blo.y, blo.z, blo.w, bhi.x, bhi.y, bhi.z, bhi.w};
#pragma unroll
                for (int i = 0; i < 8; i++)
#pragma unroll
                    for (int j = 0; j < 8; j++)
                        c2[i][j] = fmaf(a[i], b[j], c2[i][j]);
            }
            __syncthreads();
        }
        // scatter-accumulate into out
#pragma unroll
        for (int i = 0; i < 8; i++) {
            int r = ty * 8 + i;
            if (m0 + r < n_e) {
                float* orow = out + (size_t)ids_s[r] * D_DIM + dd + tx * 8;
#pragma unroll
                for (int j = 0; j < 8; j++) atomicAdd(&orow[j], c2[i][j]);
            }
        }
    }
}

extern "C" void kernel_launch(void* const* d_in, const int* in_sizes, int n_in,
                              void* d_out, int out_size, void* d_ws, size_t ws_size,
                              hipStream_t stream) {
    const float* x  = (const float*)d_in[0];
    const float* Wr = (const float*)d_in[1];
    const float* br = (const float*)d_in[2];
    const float* W1 = (const float*)d_in[3];
    const float* b1 = (const float*)d_in[4];
    const float* W2 = (const float*)d_in[5];
    const float* b2 = (const float*)d_in[6];
    float* out = (float*)d_out;

    // ws layout: [0,64) counts, [64, 64+E*T*4) tok_id, then tok_w  (~320 KB)
    int*   counts = (int*)d_ws;
    int*   tok_id = (int*)((char*)d_ws + 64);
    float* tok_w  = (float*)((char*)d_ws + 64 + E_EXP * T_TOKENS * 4);

    hipMemsetAsync(d_ws, 0, 64, stream);

    moe_router_kernel<<<T_TOKENS / 4, 256, 0, stream>>>(
        x, Wr, br, b2, out, counts, tok_id, tok_w);

    dim3 grid(H_DIM / BH, T_TOKENS / BT, E_EXP);
    moe_ffn_kernel<<<grid, 256, 0, stream>>>(
        x, W1, b1, W2, out, counts, tok_id, tok_w);
}

// Round 2
// 818.308 us; speedup vs baseline: 10.2356x; 10.2356x over previous
//
#include <hip/hip_runtime.h>
#include <math.h>

#define T_TOKENS 4096
#define D_DIM    1024
#define E_EXP    8
#define H_DIM    4096
#define NSLOT    8192   // T_TOKENS * K(=2)

// LDS tile row stride: 40 bf16 = 80 B. 16B-aligned rows (b128-friendly) and
// 20-dword stride => fragment b128 reads are <=2-way bank aliased (free, m136).
#define LDSTRIDE 40

typedef __attribute__((ext_vector_type(8))) short   short8;   // 8 bf16 = 4 VGPRs
typedef __attribute__((ext_vector_type(4))) float   floatx4;  // MFMA C/D

__device__ __forceinline__ unsigned short f2bf(float f) {   // RNE f32->bf16
    unsigned int u = __float_as_uint(f);
    u += 0x7fffu + ((u >> 16) & 1u);
    return (unsigned short)(u >> 16);
}

// ---------------- Router: scores, top-2, softmax weights, expert bucketing ----
__global__ __launch_bounds__(256)
void moe_router_kernel(const float* __restrict__ x,
                       const float* __restrict__ Wr,
                       const float* __restrict__ br,
                       const float* __restrict__ b2,
                       float* __restrict__ out,
                       int* __restrict__ counts,
                       int* __restrict__ tok_id,
                       float* __restrict__ tok_w)
{
    const int token = blockIdx.x * 4 + (threadIdx.x >> 6);
    const int lane  = threadIdx.x & 63;

    float s[E_EXP];
#pragma unroll
    for (int e = 0; e < E_EXP; e++) s[e] = 0.0f;

    const float* xrow = x + (size_t)token * D_DIM;
#pragma unroll
    for (int i = 0; i < D_DIM / 64; i++) {
        int d = lane + 64 * i;
        float xv = xrow[d];
        const float4* wr4 = (const float4*)(Wr + (size_t)d * E_EXP);
        float4 w0 = wr4[0], w1 = wr4[1];
        s[0] = fmaf(xv, w0.x, s[0]); s[1] = fmaf(xv, w0.y, s[1]);
        s[2] = fmaf(xv, w0.z, s[2]); s[3] = fmaf(xv, w0.w, s[3]);
        s[4] = fmaf(xv, w1.x, s[4]); s[5] = fmaf(xv, w1.y, s[5]);
        s[6] = fmaf(xv, w1.z, s[6]); s[7] = fmaf(xv, w1.w, s[7]);
    }
#pragma unroll
    for (int off = 32; off >= 1; off >>= 1) {
#pragma unroll
        for (int e = 0; e < E_EXP; e++) s[e] += __shfl_xor(s[e], off, 64);
    }
#pragma unroll
    for (int e = 0; e < E_EXP; e++) s[e] += br[e];

    int e0 = 0; float v0 = s[0];
#pragma unroll
    for (int e = 1; e < E_EXP; e++) if (s[e] > v0) { v0 = s[e]; e0 = e; }
    int e1 = (e0 == 0) ? 1 : 0; float v1 = s[e1];
#pragma unroll
    for (int e = 0; e < E_EXP; e++)
        if (e != e0 && s[e] > v1) { v1 = s[e]; e1 = e; }

    float p1 = __expf(v1 - v0);
    float inv = 1.0f / (1.0f + p1);
    float w0 = inv, w1 = p1 * inv;

    if (lane == 0) {
        int slot0 = atomicAdd(&counts[e0], 1);
        tok_id[e0 * T_TOKENS + slot0] = token;
        tok_w [e0 * T_TOKENS + slot0] = w0;
        int slot1 = atomicAdd(&counts[e1], 1);
        tok_id[e1 * T_TOKENS + slot1] = token;
        tok_w [e1 * T_TOKENS + slot1] = w1;
    }

    // out = w0*b2[e0] + w1*b2[e1]; FFN2 atomically adds the GEMM part on top.
    float* orow = out + (size_t)token * D_DIM;
    const float* b20 = b2 + (size_t)e0 * D_DIM;
    const float* b21 = b2 + (size_t)e1 * D_DIM;
#pragma unroll
    for (int i = 0; i < D_DIM / 64; i++) {
        int d = lane + 64 * i;
        orow[d] = fmaf(w0, b20[d], w1 * b21[d]);
    }
}

// ---------------- tiny exclusive prefix over the 8 expert counts -------------
__global__ void moe_scan_kernel(const int* __restrict__ counts,
                                int* __restrict__ offs)
{
    if (threadIdx.x == 0) {
        int a = 0;
#pragma unroll
        for (int e = 0; e < E_EXP; e++) { offs[e] = a; a += counts[e]; }
    }
}

// ---------------- FFN1: H[slot, h-chunk] = relu(Xg @ W1 + b1) * w  (bf16) ----
// grid (H/128, 32, E), 256 thr = 4 waves in 2x2; wave computes 64x64 via MFMA.
__global__ __launch_bounds__(256, 2)
void moe_ffn1_kernel(const float* __restrict__ x,
                     const float* __restrict__ W1,
                     const float* __restrict__ b1,
                     const int* __restrict__ counts,
                     const int* __restrict__ offs,
                     const int* __restrict__ tok_id,
                     const float* __restrict__ tok_w,
                     unsigned short* __restrict__ Hbuf)
{
    const int e   = blockIdx.z;
    const int n_e = counts[e];
    const int m0  = blockIdx.y * 128;
    if (m0 >= n_e) return;
    const int h0  = blockIdx.x * 128;
    const int hb  = offs[e];
    const int tid  = threadIdx.x;
    const int lane = tid & 63;
    const int wave = tid >> 6;
    const int wy = (wave >> 1) * 64;   // token offset in tile
    const int wx = (wave & 1) * 64;    // h offset in tile
    const int ml = lane & 15;
    const int q  = lane >> 4;

    __shared__ unsigned short xs[128 * LDSTRIDE];  // A: [token][k]
    __shared__ unsigned short wt[128 * LDSTRIDE];  // B: [h][k] (W1 transposed)
    __shared__ int   ids_s[128];
    __shared__ float wts_s[128];
    __shared__ float b1s[128];

    if (tid < 128) {
        int slot = m0 + tid;
        ids_s[tid] = (slot < n_e) ? tok_id[e * T_TOKENS + slot] : 0;
        wts_s[tid] = (slot < n_e) ? tok_w[e * T_TOKENS + slot] : 0.0f;
        b1s[tid]   = b1[(size_t)e * H_DIM + h0 + tid];
    }
    __syncthreads();

    floatx4 zero = {0.f, 0.f, 0.f, 0.f};
    floatx4 acc[4][4];
#pragma unroll
    for (int i = 0; i < 4; i++)
#pragma unroll
        for (int j = 0; j < 4; j++) acc[i][j] = zero;

    const float* W1e = W1 + (size_t)e * D_DIM * H_DIM + h0;
    const int xr = tid >> 1;            // x staging: row
    const int xc = (tid & 1) * 16;      // x staging: 16-col half
    const int wc = tid & 31;            // W staging: col lane
    const int wk = tid >> 5;            // W staging: k lane (0..7)
    const size_t xrow_base = (size_t)ids_s[xr] * D_DIM;

    for (int kk = 0; kk < D_DIM; kk += 32) {
        // stage X gather: 128 rows x 32 k, fp32 -> bf16
        {
            const float* src = x + xrow_base + kk + xc;
            unsigned short* dst = &xs[xr * LDSTRIDE + xc];
#pragma unroll
            for (int i = 0; i < 4; i++) {
                float4 v = *(const float4*)(src + 4 * i);
                ushort4 o = make_ushort4(f2bf(v.x), f2bf(v.y), f2bf(v.z), f2bf(v.w));
                *(ushort4*)(dst + 4 * i) = o;
            }
        }
        // stage W1 chunk transposed: global [k][h] -> LDS [h][k]
#pragma unroll
        for (int it = 0; it < 4; it++) {
            int k = wk + 8 * it;
            const float* src = W1e + (size_t)(kk + k) * H_DIM + wc;
#pragma unroll
            for (int j = 0; j < 4; j++)
                wt[(wc + 32 * j) * LDSTRIDE + k] = f2bf(src[32 * j]);
        }
        __syncthreads();

        short8 a[4], b[4];
#pragma unroll
        for (int i = 0; i < 4; i++)
            a[i] = *(const short8*)&xs[(wy + i * 16 + ml) * LDSTRIDE + q * 8];
#pragma unroll
        for (int j = 0; j < 4; j++)
            b[j] = *(const short8*)&wt[(wx + j * 16 + ml) * LDSTRIDE + q * 8];
#pragma unroll
        for (int i = 0; i < 4; i++)
#pragma unroll
            for (int j = 0; j < 4; j++)
                acc[i][j] = __builtin_amdgcn_mfma_f32_16x16x32_bf16(
                                a[i], b[j], acc[i][j], 0, 0, 0);
        __syncthreads();
    }

    // epilogue: bias + relu + token weight -> Hbuf (bf16)
#pragma unroll
    for (int i = 0; i < 4; i++) {
#pragma unroll
        for (int r = 0; r < 4; r++) {
            int row  = wy + i * 16 + q * 4 + r;   // C/D: row = quad*4+reg
            int slot = m0 + row;
            if (slot < n_e) {
                float w = wts_s[row];
                size_t base = (size_t)(hb + slot) * H_DIM + h0 + wx;
#pragma unroll
                for (int j = 0; j < 4; j++) {
                    float v = acc[i][j][r] + b1s[wx + j * 16 + ml];
                    v = fmaxf(v, 0.0f) * w;
                    Hbuf[base + j * 16 + ml] = f2bf(v);
                }
            }
        }
    }
}

// ---------------- FFN2: out[token, d-chunk] += H[slot,:] @ W2 ----------------
// grid (D/128, 32, E); K = 4096 full per block => 1 atomic add per expert-token
// per out element (8.4M total vs 268M before).
__global__ __launch_bounds__(256, 2)
void moe_ffn2_kernel(const float* __restrict__ W2,
                     float* __restrict__ out,
                     const int* __restrict__ counts,
                     const int* __restrict__ offs,
                     const int* __restrict__ tok_id,
                     const unsigned short* __restrict__ Hbuf)
{
    const int e   = blockIdx.z;
    const int n_e = counts[e];
    const int m0  = blockIdx.y * 128;
    if (m0 >= n_e) return;
    const int d0  = blockIdx.x * 128;
    const int hb  = offs[e];
    const int tid  = threadIdx.x;
    const int lane = tid & 63;
    const int wave = tid >> 6;
    const int wy = (wave >> 1) * 64;
    const int wx = (wave & 1) * 64;
    const int ml = lane & 15;
    const int q  = lane >> 4;

    __shared__ unsigned short hs[128 * LDSTRIDE];  // A: [slot][k]
    __shared__ unsigned short wt[128 * LDSTRIDE];  // B: [d][k] (W2 transposed)
    __shared__ int ids_s[128];

    if (tid < 128) {
        int slot = m0 + tid;
        ids_s[tid] = (slot < n_e) ? tok_id[e * T_TOKENS + slot] : 0;
    }
    __syncthreads();

    floatx4 zero = {0.f, 0.f, 0.f, 0.f};
    floatx4 acc[4][4];
#pragma unroll
    for (int i = 0; i < 4; i++)
#pragma unroll
        for (int j = 0; j < 4; j++) acc[i][j] = zero;

    const float* W2e = W2 + (size_t)e * H_DIM * D_DIM + d0;
    const int xr = tid >> 1;
    const int xc = (tid & 1) * 16;
    const int wc = tid & 31;
    const int wk = tid >> 5;
    // clamp pad rows so we never read past Hbuf (their output is discarded)
    const int hrow = min(hb + m0 + xr, NSLOT - 1);
    const size_t hrow_base = (size_t)hrow * H_DIM;

    for (int kk = 0; kk < H_DIM; kk += 32) {
        // stage H tile (already bf16): 128 rows x 32 k
        {
            const unsigned short* src = Hbuf + hrow_base + kk + xc;
            unsigned short* dst = &hs[xr * LDSTRIDE + xc];
#pragma unroll
            for (int i = 0; i < 4; i++)
                *(ushort4*)(dst + 4 * i) = *(const ushort4*)(src + 4 * i);
        }
        // stage W2 chunk transposed: global [k][d] -> LDS [d][k]
#pragma unroll
        for (int it = 0; it < 4; it++) {
            int k = wk + 8 * it;
            const float* src = W2e + (size_t)(kk + k) * D_DIM + wc;
#pragma unroll
            for (int j = 0; j < 4; j++)
                wt[(wc + 32 * j) * LDSTRIDE + k] = f2bf(src[32 * j]);
        }
        __syncthreads();

        short8 a[4], b[4];
#pragma unroll
        for (int i = 0; i < 4; i++)
            a[i] = *(const short8*)&hs[(wy + i * 16 + ml) * LDSTRIDE + q * 8];
#pragma unroll
        for (int j = 0; j < 4; j++)
            b[j] = *(const short8*)&wt[(wx + j * 16 + ml) * LDSTRIDE + q * 8];
#pragma unroll
        for (int i = 0; i < 4; i++)
#pragma unroll
            for (int j = 0; j < 4; j++)
                acc[i][j] = __builtin_amdgcn_mfma_f32_16x16x32_bf16(
                                a[i], b[j], acc[i][j], 0, 0, 0);
        __syncthreads();
    }

    // epilogue: one atomicAdd per element (token weight already folded into H)
#pragma unroll
    for (int i = 0; i < 4; i++) {
#pragma unroll
        for (int r = 0; r < 4; r++) {
            int row  = wy + i * 16 + q * 4 + r;
            int slot = m0 + row;
            if (slot < n_e) {
                float* orow = out + (size_t)ids_s[row] * D_DIM + d0 + wx;
#pragma unroll
                for (int j = 0; j < 4; j++)
                    atomicAdd(&orow[j * 16 + ml], acc[i][j][r]);
            }
        }
    }
}

extern "C" void kernel_launch(void* const* d_in, const int* in_sizes, int n_in,
                              void* d_out, int out_size, void* d_ws, size_t ws_size,
                              hipStream_t stream) {
    const float* x  = (const float*)d_in[0];
    const float* Wr = (const float*)d_in[1];
    const float* br = (const float*)d_in[2];
    const float* W1 = (const float*)d_in[3];
    const float* b1 = (const float*)d_in[4];
    const float* W2 = (const float*)d_in[5];
    const float* b2 = (const float*)d_in[6];
    float* out = (float*)d_out;

    // ws layout: counts(64) | offs(64) | tok_id(128K) | tok_w(128K) | pad |
    //            Hbuf bf16 [8192 x 4096] at 512K  => ~64.5 MB total
    int*   counts = (int*)d_ws;
    int*   offs   = (int*)((char*)d_ws + 64);
    int*   tok_id = (int*)((char*)d_ws + 128);
    float* tok_w  = (float*)((char*)d_ws + 128 + E_EXP * T_TOKENS * 4);
    unsigned short* Hbuf = (unsigned short*)((char*)d_ws + 524288);

    hipMemsetAsync(d_ws, 0, 64, stream);

    moe_router_kernel<<<T_TOKENS / 4, 256, 0, stream>>>(
        x, Wr, br, b2, out, counts, tok_id, tok_w);
    moe_scan_kernel<<<1, 64, 0, stream>>>(counts, offs);

    dim3 g1(H_DIM / 128, T_TOKENS / 128, E_EXP);
    moe_ffn1_kernel<<<g1, 256, 0, stream>>>(
        x, W1, b1, counts, offs, tok_id, tok_w, Hbuf);

    dim3 g2(D_DIM / 128, T_TOKENS / 128, E_EXP);
    moe_ffn2_kernel<<<g2, 256, 0, stream>>>(
        W2, out, counts, offs, tok_id, Hbuf);
}

// Round 3
// 631.276 us; speedup vs baseline: 13.2681x; 1.2963x over previous
//
#include <hip/hip_runtime.h>
#include <math.h>

#define T_TOKENS 4096
#define D_DIM    1024
#define E_EXP    8
#define H_DIM    4096
#define NSLOT    8192            // T_TOKENS * K(=2)
#define NSLOTP   (NSLOT + 128)   // pad so GEMM tail tiles stay in-bounds

#define LDSTRIDE 40              // fallback-path LDS stride

typedef __attribute__((ext_vector_type(8))) short   short8;   // 8 bf16 = 4 VGPRs
typedef __attribute__((ext_vector_type(4))) float   floatx4;  // MFMA C/D

__device__ __forceinline__ unsigned short f2bf(float f) {   // RNE f32->bf16
    unsigned int u = __float_as_uint(f);
    u += 0x7fffu + ((u >> 16) & 1u);
    return (unsigned short)(u >> 16);
}
__device__ __forceinline__ short8 pack8(const float4 a, const float4 b) {
    short8 r;
    r[0] = (short)f2bf(a.x); r[1] = (short)f2bf(a.y);
    r[2] = (short)f2bf(a.z); r[3] = (short)f2bf(a.w);
    r[4] = (short)f2bf(b.x); r[5] = (short)f2bf(b.y);
    r[6] = (short)f2bf(b.z); r[7] = (short)f2bf(b.w);
    return r;
}

// async 16B global -> LDS (lds dest must be wave-uniform; HW adds lane*16)
typedef __attribute__((address_space(1))) const unsigned int guint;
typedef __attribute__((address_space(3))) unsigned int luint;
__device__ __forceinline__ void gl_lds16(const void* g, void* l) {
    __builtin_amdgcn_global_load_lds((guint*)g, (luint*)l, 16, 0, 0);
}

// ---------------- Router: scores, top-2, softmax weights, expert bucketing ----
__global__ __launch_bounds__(256)
void moe_router_kernel(const float* __restrict__ x,
                       const float* __restrict__ Wr,
                       const float* __restrict__ br,
                       const float* __restrict__ b2,
                       float* __restrict__ out,
                       int* __restrict__ counts,
                       int* __restrict__ tok_id,
                       float* __restrict__ tok_w)
{
    const int token = blockIdx.x * 4 + (threadIdx.x >> 6);
    const int lane  = threadIdx.x & 63;

    float s[E_EXP];
#pragma unroll
    for (int e = 0; e < E_EXP; e++) s[e] = 0.0f;

    const float* xrow = x + (size_t)token * D_DIM;
#pragma unroll
    for (int i = 0; i < D_DIM / 64; i++) {
        int d = lane + 64 * i;
        float xv = xrow[d];
        const float4* wr4 = (const float4*)(Wr + (size_t)d * E_EXP);
        float4 w0 = wr4[0], w1 = wr4[1];
        s[0] = fmaf(xv, w0.x, s[0]); s[1] = fmaf(xv, w0.y, s[1]);
        s[2] = fmaf(xv, w0.z, s[2]); s[3] = fmaf(xv, w0.w, s[3]);
        s[4] = fmaf(xv, w1.x, s[4]); s[5] = fmaf(xv, w1.y, s[5]);
        s[6] = fmaf(xv, w1.z, s[6]); s[7] = fmaf(xv, w1.w, s[7]);
    }
#pragma unroll
    for (int off = 32; off >= 1; off >>= 1) {
#pragma unroll
        for (int e = 0; e < E_EXP; e++) s[e] += __shfl_xor(s[e], off, 64);
    }
#pragma unroll
    for (int e = 0; e < E_EXP; e++) s[e] += br[e];

    int e0 = 0; float v0 = s[0];
#pragma unroll
    for (int e = 1; e < E_EXP; e++) if (s[e] > v0) { v0 = s[e]; e0 = e; }
    int e1 = (e0 == 0) ? 1 : 0; float v1 = s[e1];
#pragma unroll
    for (int e = 0; e < E_EXP; e++)
        if (e != e0 && s[e] > v1) { v1 = s[e]; e1 = e; }

    float p1 = __expf(v1 - v0);
    float inv = 1.0f / (1.0f + p1);
    float w0 = inv, w1 = p1 * inv;

    if (lane == 0) {
        int slot0 = atomicAdd(&counts[e0], 1);
        tok_id[e0 * T_TOKENS + slot0] = token;
        tok_w [e0 * T_TOKENS + slot0] = w0;
        int slot1 = atomicAdd(&counts[e1], 1);
        tok_id[e1 * T_TOKENS + slot1] = token;
        tok_w [e1 * T_TOKENS + slot1] = w1;
    }

    float* orow = out + (size_t)token * D_DIM;
    const float* b20 = b2 + (size_t)e0 * D_DIM;
    const float* b21 = b2 + (size_t)e1 * D_DIM;
#pragma unroll
    for (int i = 0; i < D_DIM / 64; i++) {
        int d = lane + 64 * i;
        orow[d] = fmaf(w0, b20[d], w1 * b21[d]);
    }
}

__global__ void moe_scan_kernel(const int* __restrict__ counts,
                                int* __restrict__ offs)
{
    if (threadIdx.x == 0) {
        int a = 0;
#pragma unroll
        for (int e = 0; e < E_EXP; e++) { offs[e] = a; a += counts[e]; }
    }
}

// =====================  FAST PATH (needs ~146 MiB ws)  =======================

// Xg[(d/8)][gslot][8] bf16: gathered+swizzled activations. grid (32, 8) x 256.
__global__ __launch_bounds__(256)
void moe_xgather_kernel(const float* __restrict__ x,
                        const int* __restrict__ offs,
                        const int* __restrict__ tok_id,
                        unsigned short* __restrict__ Xg)
{
    const int gslot = blockIdx.x * 256 + threadIdx.x;   // 0..8191
    int e = 0;
#pragma unroll
    for (int i = 1; i < E_EXP; i++) if (gslot >= offs[i]) e = i;
    const int loc = gslot - offs[e];
    const int token = tok_id[e * T_TOKENS + loc];
    const float* xr = x + (size_t)token * D_DIM;
    const int g0 = blockIdx.y * 16;
#pragma unroll
    for (int g = g0; g < g0 + 16; g++) {
        float4 v0 = *(const float4*)(xr + g * 8);
        float4 v1 = *(const float4*)(xr + g * 8 + 4);
        *(short8*)&Xg[((size_t)g * NSLOTP + gslot) * 8] = pack8(v0, v1);
    }
}

// W stage: S[e][((r/8)*C + c)*8 + r%8] = bf16(M[e][r][c]).  r = contraction dim.
// grid (C/64, R/64, E) x 256.
__global__ __launch_bounds__(256)
void moe_wstage_kernel(const float* __restrict__ M,
                       unsigned short* __restrict__ S,
                       int R, int C)
{
    __shared__ unsigned short T[64 * 72];   // T[c_local][r_local], 16B-aligned rows
    const int e = blockIdx.z;
    const float* Me = M + (size_t)e * R * C;
    unsigned short* Se = S + (size_t)e * R * C;
    const int c0 = blockIdx.x * 64, r0 = blockIdx.y * 64;
    const int tid = threadIdx.x;
    const int rl = tid >> 2, cc = (tid & 3) * 16;

    const float* src = Me + (size_t)(r0 + rl) * C + c0 + cc;
#pragma unroll
    for (int j = 0; j < 4; j++) {
        float4 v = *(const float4*)(src + 4 * j);
        T[(cc + 4 * j + 0) * 72 + rl] = f2bf(v.x);
        T[(cc + 4 * j + 1) * 72 + rl] = f2bf(v.y);
        T[(cc + 4 * j + 2) * 72 + rl] = f2bf(v.z);
        T[(cc + 4 * j + 3) * 72 + rl] = f2bf(v.w);
    }
    __syncthreads();
#pragma unroll
    for (int it = 0; it < 2; it++) {
        int cell = tid + 256 * it;
        int c = cell & 63, g = cell >> 6;
        short8 v = *(const short8*)&T[c * 72 + g * 8];
        *(short8*)&Se[(((size_t)(r0 >> 3) + g) * C + c0 + c) * 8] = v;
    }
}

// FFN1 fast: Hbuf = relu(Xg @ W1S + b1) * w, swizzled out. grid (32, 32, 8).
__global__ __launch_bounds__(256, 2)
void moe_ffn1_fast(const unsigned short* __restrict__ Xg,
                   const unsigned short* __restrict__ W1S,
                   const float* __restrict__ b1,
                   const int* __restrict__ counts,
                   const int* __restrict__ offs,
                   const float* __restrict__ tok_w,
                   unsigned short* __restrict__ Hbuf)
{
    const int e   = blockIdx.z;
    const int n_e = counts[e];
    const int m0  = blockIdx.y * 128;
    if (m0 >= n_e) return;
    const int h0  = blockIdx.x * 128;
    const int hb  = offs[e];
    const int tid  = threadIdx.x;
    const int lane = tid & 63;
    const int wave = tid >> 6;
    const int wy = (wave >> 1) * 64, wx = (wave & 1) * 64;
    const int ml = lane & 15, q = lane >> 4;

    __shared__ unsigned short As[8 * 128 * 8];   // 16 KB, [g][row][8]
    __shared__ unsigned short Bs[8 * 128 * 8];   // 16 KB
    __shared__ float wts_s[128];
    __shared__ float b1s[128];

    if (tid < 128) {
        int slot = m0 + tid;
        wts_s[tid] = (slot < n_e) ? tok_w[e * T_TOKENS + slot] : 0.0f;
        b1s[tid]   = b1[(size_t)e * H_DIM + h0 + tid];
    }

    floatx4 zero = {0.f, 0.f, 0.f, 0.f};
    floatx4 acc[4][4];
#pragma unroll
    for (int i = 0; i < 4; i++)
#pragma unroll
        for (int j = 0; j < 4; j++) acc[i][j] = zero;

    const unsigned short* Be = W1S + (size_t)e * D_DIM * H_DIM;
    const size_t arow = (size_t)(hb + m0);
    const int cell = ((0 * 4 + wave) * 64) + lane;  // recomputed per t below

    for (int kk8 = 0; kk8 < D_DIM / 8; kk8 += 8) {   // BK = 64
#pragma unroll
        for (int t = 0; t < 4; t++) {
            int cbase = (t * 4 + wave) * 64;          // wave-uniform
            int c = cbase + lane;
            int g = c >> 7, r = c & 127;
            gl_lds16(&Xg[((size_t)(kk8 + g) * NSLOTP + arow + r) * 8], &As[cbase * 8]);
            gl_lds16(&Be[((size_t)(kk8 + g) * H_DIM + h0 + r) * 8],    &Bs[cbase * 8]);
        }
        __syncthreads();
#pragma unroll
        for (int ks = 0; ks < 2; ks++) {
            short8 a[4], b[4];
#pragma unroll
            for (int i = 0; i < 4; i++)
                a[i] = *(const short8*)&As[(((ks * 4 + q) * 128) + wy + i * 16 + ml) * 8];
#pragma unroll
            for (int j = 0; j < 4; j++)
                b[j] = *(const short8*)&Bs[(((ks * 4 + q) * 128) + wx + j * 16 + ml) * 8];
#pragma unroll
            for (int i = 0; i < 4; i++)
#pragma unroll
                for (int j = 0; j < 4; j++)
                    acc[i][j] = __builtin_amdgcn_mfma_f32_16x16x32_bf16(
                                    a[i], b[j], acc[i][j], 0, 0, 0);
        }
        __syncthreads();
    }
    (void)cell;

    // epilogue -> Hbuf[(h/8)][gslot][8]
#pragma unroll
    for (int i = 0; i < 4; i++) {
#pragma unroll
        for (int r = 0; r < 4; r++) {
            int row  = wy + i * 16 + q * 4 + r;
            int slot = m0 + row;
            if (slot < n_e) {
                float w = wts_s[row];
                int gslot = hb + slot;
#pragma unroll
                for (int j = 0; j < 4; j++) {
                    int hcol = h0 + wx + j * 16 + ml;
                    float v = fmaxf(acc[i][j][r] + b1s[wx + j * 16 + ml], 0.0f) * w;
                    Hbuf[((size_t)(hcol >> 3) * NSLOTP + gslot) * 8 + (hcol & 7)] = f2bf(v);
                }
            }
        }
    }
}

// FFN2 fast: out += Hbuf @ W2S (K-split 2). grid (16, 32, 8).
__global__ __launch_bounds__(256, 2)
void moe_ffn2_fast(const unsigned short* __restrict__ Hbuf,
                   const unsigned short* __restrict__ W2S,
                   float* __restrict__ out,
                   const int* __restrict__ counts,
                   const int* __restrict__ offs,
                   const int* __restrict__ tok_id)
{
    const int e   = blockIdx.z;
    const int n_e = counts[e];
    const int m0  = blockIdx.y * 128;
    if (m0 >= n_e) return;
    const int d0  = (blockIdx.x & 7) * 128;
    const int kb  = (blockIdx.x >> 3) * (H_DIM / 8 / 2);  // kgrp base: 0 or 256
    const int hb  = offs[e];
    const int tid  = threadIdx.x;
    const int lane = tid & 63;
    const int wave = tid >> 6;
    const int wy = (wave >> 1) * 64, wx = (wave & 1) * 64;
    const int ml = lane & 15, q = lane >> 4;

    __shared__ unsigned short As[8 * 128 * 8];
    __shared__ unsigned short Bs[8 * 128 * 8];
    __shared__ int ids_s[128];

    if (tid < 128) {
        int slot = m0 + tid;
        ids_s[tid] = (slot < n_e) ? tok_id[e * T_TOKENS + slot] : 0;
    }

    floatx4 zero = {0.f, 0.f, 0.f, 0.f};
    floatx4 acc[4][4];
#pragma unroll
    for (int i = 0; i < 4; i++)
#pragma unroll
        for (int j = 0; j < 4; j++) acc[i][j] = zero;

    const unsigned short* Be = W2S + (size_t)e * H_DIM * D_DIM;
    const size_t arow = (size_t)(hb + m0);

    for (int kk8 = kb; kk8 < kb + H_DIM / 8 / 2; kk8 += 8) {   // 32 iters of BK=64
#pragma unroll
        for (int t = 0; t < 4; t++) {
            int cbase = (t * 4 + wave) * 64;
            int c = cbase + lane;
            int g = c >> 7, r = c & 127;
            gl_lds16(&Hbuf[((size_t)(kk8 + g) * NSLOTP + arow + r) * 8], &As[cbase * 8]);
            gl_lds16(&Be[((size_t)(kk8 + g) * D_DIM + d0 + r) * 8],      &Bs[cbase * 8]);
        }
        __syncthreads();
#pragma unroll
        for (int ks = 0; ks < 2; ks++) {
            short8 a[4], b[4];
#pragma unroll
            for (int i = 0; i < 4; i++)
                a[i] = *(const short8*)&As[(((ks * 4 + q) * 128) + wy + i * 16 + ml) * 8];
#pragma unroll
            for (int j = 0; j < 4; j++)
                b[j] = *(const short8*)&Bs[(((ks * 4 + q) * 128) + wx + j * 16 + ml) * 8];
#pragma unroll
            for (int i = 0; i < 4; i++)
#pragma unroll
                for (int j = 0; j < 4; j++)
                    acc[i][j] = __builtin_amdgcn_mfma_f32_16x16x32_bf16(
                                    a[i], b[j], acc[i][j], 0, 0, 0);
        }
        __syncthreads();
    }

#pragma unroll
    for (int i = 0; i < 4; i++) {
#pragma unroll
        for (int r = 0; r < 4; r++) {
            int row  = wy + i * 16 + q * 4 + r;
            int slot = m0 + row;
            if (slot < n_e) {
                float* orow = out + (size_t)ids_s[row] * D_DIM + d0 + wx;
#pragma unroll
                for (int j = 0; j < 4; j++)
                    atomicAdd(&orow[j * 16 + ml], acc[i][j][r]);
            }
        }
    }
}

// =====================  FALLBACK PATH (round-2, proven)  =====================

__global__ __launch_bounds__(256, 2)
void moe_ffn1_kernel(const float* __restrict__ x,
                     const float* __restrict__ W1,
                     const float* __restrict__ b1,
                     const int* __restrict__ counts,
                     const int* __restrict__ offs,
                     const int* __restrict__ tok_id,
                     const float* __restrict__ tok_w,
                     unsigned short* __restrict__ Hbuf)
{
    const int e   = blockIdx.z;
    const int n_e = counts[e];
    const int m0  = blockIdx.y * 128;
    if (m0 >= n_e) return;
    const int h0  = blockIdx.x * 128;
    const int hb  = offs[e];
    const int tid  = threadIdx.x;
    const int lane = tid & 63;
    const int wave = tid >> 6;
    const int wy = (wave >> 1) * 64;
    const int wx = (wave & 1) * 64;
    const int ml = lane & 15;
    const int q  = lane >> 4;

    __shared__ unsigned short xs[128 * LDSTRIDE];
    __shared__ unsigned short wt[128 * LDSTRIDE];
    __shared__ int   ids_s[128];
    __shared__ float wts_s[128];
    __shared__ float b1s[128];

    if (tid < 128) {
        int slot = m0 + tid;
        ids_s[tid] = (slot < n_e) ? tok_id[e * T_TOKENS + slot] : 0;
        wts_s[tid] = (slot < n_e) ? tok_w[e * T_TOKENS + slot] : 0.0f;
        b1s[tid]   = b1[(size_t)e * H_DIM + h0 + tid];
    }
    __syncthreads();

    floatx4 zero = {0.f, 0.f, 0.f, 0.f};
    floatx4 acc[4][4];
#pragma unroll
    for (int i = 0; i < 4; i++)
#pragma unroll
        for (int j = 0; j < 4; j++) acc[i][j] = zero;

    const float* W1e = W1 + (size_t)e * D_DIM * H_DIM + h0;
    const int xr = tid >> 1;
    const int xc = (tid & 1) * 16;
    const int wc = tid & 31;
    const int wk = tid >> 5;
    const size_t xrow_base = (size_t)ids_s[xr] * D_DIM;

    for (int kk = 0; kk < D_DIM; kk += 32) {
        {
            const float* src = x + xrow_base + kk + xc;
            unsigned short* dst = &xs[xr * LDSTRIDE + xc];
#pragma unroll
            for (int i = 0; i < 4; i++) {
                float4 v = *(const float4*)(src + 4 * i);
                ushort4 o = make_ushort4(f2bf(v.x), f2bf(v.y), f2bf(v.z), f2bf(v.w));
                *(ushort4*)(dst + 4 * i) = o;
            }
        }
#pragma unroll
        for (int it = 0; it < 4; it++) {
            int k = wk + 8 * it;
            const float* src = W1e + (size_t)(kk + k) * H_DIM + wc;
#pragma unroll
            for (int j = 0; j < 4; j++)
                wt[(wc + 32 * j) * LDSTRIDE + k] = f2bf(src[32 * j]);
        }
        __syncthreads();

        short8 a[4], b[4];
#pragma unroll
        for (int i = 0; i < 4; i++)
            a[i] = *(const short8*)&xs[(wy + i * 16 + ml) * LDSTRIDE + q * 8];
#pragma unroll
        for (int j = 0; j < 4; j++)
            b[j] = *(const short8*)&wt[(wx + j * 16 + ml) * LDSTRIDE + q * 8];
#pragma unroll
        for (int i = 0; i < 4; i++)
#pragma unroll
            for (int j = 0; j < 4; j++)
                acc[i][j] = __builtin_amdgcn_mfma_f32_16x16x32_bf16(
                                a[i], b[j], acc[i][j], 0, 0, 0);
        __syncthreads();
    }

#pragma unroll
    for (int i = 0; i < 4; i++) {
#pragma unroll
        for (int r = 0; r < 4; r++) {
            int row  = wy + i * 16 + q * 4 + r;
            int slot = m0 + row;
            if (slot < n_e) {
                float w = wts_s[row];
                size_t base = (size_t)(hb + slot) * H_DIM + h0 + wx;
#pragma unroll
                for (int j = 0; j < 4; j++) {
                    float v = acc[i][j][r] + b1s[wx + j * 16 + ml];
                    v = fmaxf(v, 0.0f) * w;
                    Hbuf[base + j * 16 + ml] = f2bf(v);
                }
            }
        }
    }
}

__global__ __launch_bounds__(256, 2)
void moe_ffn2_kernel(const float* __restrict__ W2,
                     float* __restrict__ out,
                     const int* __restrict__ counts,
                     const int* __restrict__ offs,
                     const int* __restrict__ tok_id,
                     const unsigned short* __restrict__ Hbuf)
{
    const int e   = blockIdx.z;
    const int n_e = counts[e];
    const int m0  = blockIdx.y * 128;
    if (m0 >= n_e) return;
    const int d0  = blockIdx.x * 128;
    const int hb  = offs[e];
    const int tid  = threadIdx.x;
    const int lane = tid & 63;
    const int wave = tid >> 6;
    const int wy = (wave >> 1) * 64;
    const int wx = (wave & 1) * 64;
    const int ml = lane & 15;
    const int q  = lane >> 4;

    __shared__ unsigned short hs[128 * LDSTRIDE];
    __shared__ unsigned short wt[128 * LDSTRIDE];
    __shared__ int ids_s[128];

    if (tid < 128) {
        int slot = m0 + tid;
        ids_s[tid] = (slot < n_e) ? tok_id[e * T_TOKENS + slot] : 0;
    }
    __syncthreads();

    floatx4 zero = {0.f, 0.f, 0.f, 0.f};
    floatx4 acc[4][4];
#pragma unroll
    for (int i = 0; i < 4; i++)
#pragma unroll
        for (int j = 0; j < 4; j++) acc[i][j] = zero;

    const float* W2e = W2 + (size_t)e * H_DIM * D_DIM + d0;
    const int xr = tid >> 1;
    const int xc = (tid & 1) * 16;
    const int wc = tid & 31;
    const int wk = tid >> 5;
    const int hrow = min(hb + m0 + xr, NSLOT - 1);
    const size_t hrow_base = (size_t)hrow * H_DIM;

    for (int kk = 0; kk < H_DIM; kk += 32) {
        {
            const unsigned short* src = Hbuf + hrow_base + kk + xc;
            unsigned short* dst = &hs[xr * LDSTRIDE + xc];
#pragma unroll
            for (int i = 0; i < 4; i++)
                *(ushort4*)(dst + 4 * i) = *(const ushort4*)(src + 4 * i);
        }
#pragma unroll
        for (int it = 0; it < 4; it++) {
            int k = wk + 8 * it;
            const float* src = W2e + (size_t)(kk + k) * D_DIM + wc;
#pragma unroll
            for (int j = 0; j < 4; j++)
                wt[(wc + 32 * j) * LDSTRIDE + k] = f2bf(src[32 * j]);
        }
        __syncthreads();

        short8 a[4], b[4];
#pragma unroll
        for (int i = 0; i < 4; i++)
            a[i] = *(const short8*)&hs[(wy + i * 16 + ml) * LDSTRIDE + q * 8];
#pragma unroll
        for (int j = 0; j < 4; j++)
            b[j] = *(const short8*)&wt[(wx + j * 16 + ml) * LDSTRIDE + q * 8];
#pragma unroll
        for (int i = 0; i < 4; i++)
#pragma unroll
            for (int j = 0; j < 4; j++)
                acc[i][j] = __builtin_amdgcn_mfma_f32_16x16x32_bf16(
                                a[i], b[j], acc[i][j], 0, 0, 0);
        __syncthreads();
    }

#pragma unroll
    for (int i = 0; i < 4; i++) {
#pragma unroll
        for (int r = 0; r < 4; r++) {
            int row  = wy + i * 16 + q * 4 + r;
            int slot = m0 + row;
            if (slot < n_e) {
                float* orow = out + (size_t)ids_s[row] * D_DIM + d0 + wx;
#pragma unroll
                for (int j = 0; j < 4; j++)
                    atomicAdd(&orow[j * 16 + ml], acc[i][j][r]);
            }
        }
    }
}

// =============================================================================

extern "C" void kernel_launch(void* const* d_in, const int* in_sizes, int n_in,
                              void* d_out, int out_size, void* d_ws, size_t ws_size,
                              hipStream_t stream) {
    const float* x  = (const float*)d_in[0];
    const float* Wr = (const float*)d_in[1];
    const float* br = (const float*)d_in[2];
    const float* W1 = (const float*)d_in[3];
    const float* b1 = (const float*)d_in[4];
    const float* W2 = (const float*)d_in[5];
    const float* b2 = (const float*)d_in[6];
    float* out = (float*)d_out;

    int*   counts = (int*)d_ws;
    int*   offs   = (int*)((char*)d_ws + 64);
    int*   tok_id = (int*)((char*)d_ws + 128);
    float* tok_w  = (float*)((char*)d_ws + 128 + E_EXP * T_TOKENS * 4);

    // fast-path layout (1 MiB-aligned blocks):
    const size_t OFF_XG  = 1u << 20;
    const size_t SZ_XG   = (size_t)(D_DIM / 8) * NSLOTP * 16;          // 17,039,360
    const size_t OFF_W   = OFF_XG + SZ_XG;
    const size_t SZ_W    = (size_t)E_EXP * D_DIM * H_DIM * 2;          // 67,108,864
    const size_t OFF_HB  = OFF_W + SZ_W;
    const size_t SZ_HB   = (size_t)(H_DIM / 8) * NSLOTP * 16;          // 68,157,440
    const size_t NEED_FAST = OFF_HB + SZ_HB;                           // ~146 MiB

    hipMemsetAsync(d_ws, 0, 64, stream);

    moe_router_kernel<<<T_TOKENS / 4, 256, 0, stream>>>(
        x, Wr, br, b2, out, counts, tok_id, tok_w);
    moe_scan_kernel<<<1, 64, 0, stream>>>(counts, offs);

    if (ws_size >= NEED_FAST) {
        unsigned short* Xg   = (unsigned short*)((char*)d_ws + OFF_XG);
        unsigned short* Wsh  = (unsigned short*)((char*)d_ws + OFF_W);   // W1S then W2S
        unsigned short* Hbuf = (unsigned short*)((char*)d_ws + OFF_HB);

        moe_xgather_kernel<<<dim3(NSLOT / 256, 8), 256, 0, stream>>>(
            x, offs, tok_id, Xg);

        // W1S: R=D, C=H
        moe_wstage_kernel<<<dim3(H_DIM / 64, D_DIM / 64, E_EXP), 256, 0, stream>>>(
            W1, Wsh, D_DIM, H_DIM);

        moe_ffn1_fast<<<dim3(H_DIM / 128, T_TOKENS / 128, E_EXP), 256, 0, stream>>>(
            Xg, Wsh, b1, counts, offs, tok_w, Hbuf);

        // W2S overwrites the same region (stream-serial, FFN1 done): R=H, C=D
        moe_wstage_kernel<<<dim3(D_DIM / 64, H_DIM / 64, E_EXP), 256, 0, stream>>>(
            W2, Wsh, H_DIM, D_DIM);

        moe_ffn2_fast<<<dim3(16, T_TOKENS / 128, E_EXP), 256, 0, stream>>>(
            Hbuf, Wsh, out, counts, offs, tok_id);
    } else {
        unsigned short* Hbuf = (unsigned short*)((char*)d_ws + 524288);

        dim3 g1(H_DIM / 128, T_TOKENS / 128, E_EXP);
        moe_ffn1_kernel<<<g1, 256, 0, stream>>>(
            x, W1, b1, counts, offs, tok_id, tok_w, Hbuf);

        dim3 g2(D_DIM / 128, T_TOKENS / 128, E_EXP);
        moe_ffn2_kernel<<<g2, 256, 0, stream>>>(
            W2, out, counts, offs, tok_id, Hbuf);
    }
}